// Round 4
// baseline (2050.268 us; speedup 1.0000x reference)
//
#include <hip/hip_runtime.h>
#include <hip/hip_bf16.h>
#include <stdint.h>

#define B_    64
#define T_    512
#define NIN_  64
#define N_    1024
#define NOUT_ 32

// persistent-scan decomposition
#define NISL  16            // islands (independent batch groups)
#define BPI   16            // blocks per island (N-slices)
#define MB    4             // batches per island  = B_/NISL
#define COLS  64            // output cols per block = N_/BPI
#define NT    4             // 16-wide N tiles per block
#define KW    256           // K range per wave = N_/4
#define KT    8             // 32-wide K steps per wave

#define EX_WORDS (2 * B_ * (N_ / 2))   // two parity buffers of bf16x2 dwords

typedef float f32x4 __attribute__((ext_vector_type(4)));
typedef short s16x8 __attribute__((ext_vector_type(8)));

__device__ __forceinline__ unsigned short f2bf(float f) {
  union { float f; unsigned u; } v; v.f = f;
  unsigned r = v.u + 0x7FFFu + ((v.u >> 16) & 1u);   // RNE, no NaN in data
  return (unsigned short)(r >> 16);
}

__device__ __forceinline__ s16x8 cvt8(float4 a, float4 b) {
  s16x8 f;
  f[0] = (short)f2bf(a.x); f[1] = (short)f2bf(a.y);
  f[2] = (short)f2bf(a.z); f[3] = (short)f2bf(a.w);
  f[4] = (short)f2bf(b.x); f[5] = (short)f2bf(b.y);
  f[6] = (short)f2bf(b.z); f[7] = (short)f2bf(b.w);
  return f;
}

// IF$-fresh 16B load (L1 bypass via sc0, L2 bypass via sc1) with imm offset.
#define LD16(dst, base, OFF) \
  asm volatile("global_load_dwordx4 %0, %1, off offset:" #OFF " sc0 sc1" \
               : "=v"(dst) : "v"(base) : "memory")

#define LDALL() do { \
  LD16(afr[0], bp, 0);   LD16(afr[1], bp, 64);  \
  LD16(afr[2], bp, 128); LD16(afr[3], bp, 192); \
  LD16(afr[4], bp, 256); LD16(afr[5], bp, 320); \
  LD16(afr[6], bp, 384); LD16(afr[7], bp, 448); } while (0)

// ---------------------------------------------------------------------------
// Persistent scan: 256 blocks = 16 islands x 16 N-slices, W_rec resident in
// VGPRs. NO flags/atomics: the exchange is self-validating — bit 0 of every
// published dword (low bf16's LSB) carries the step tag ((t>>1)&1, which
// alternates on each reuse of a parity buffer). The consumer's poll IS the
// data load; staleness at any dword granularity is detected and retried.
// Liveness: producers never wait on consumers before publishing (forward
// progress by induction); visibility: sc1 write-through stores + sc0/sc1
// loads at the IF$ coherence point (the exact encodings that passed R2).
// ---------------------------------------------------------------------------
__global__ __launch_bounds__(256, 1) void rnn_scan(
    const float* __restrict__ U, const float* __restrict__ X0,
    const float* __restrict__ SN, const float* __restrict__ RN,
    const float* __restrict__ Wi, const float* __restrict__ Bi,
    const float* __restrict__ Wr,
    float* __restrict__ X, float* __restrict__ R,
    unsigned* __restrict__ ex)
{
  const int bid   = blockIdx.x;
  const int isl   = bid / BPI, slice = bid % BPI;
  const int tid   = threadIdx.x;
  const int wave  = tid >> 6, lane = tid & 63;
  const int l15   = lane & 15, koct = lane >> 4;
  const int colbase = slice * COLS;

  // --- resident B fragments of W_rec slice: B[k][n] = W_rec[col n][k] ---
  s16x8 bfrag[KT][NT];
#pragma unroll
  for (int kt = 0; kt < KT; ++kt) {
    const int k0 = wave * KW + kt * 32 + koct * 8;
#pragma unroll
    for (int nt = 0; nt < NT; ++nt) {
      const float4* q = (const float4*)(Wr + (size_t)(colbase + nt * 16 + l15) * N_ + k0);
      bfrag[kt][nt] = cvt8(q[0], q[1]);
    }
  }
  // --- W_in fragments: input term split across waves 0,1 (K=64 = 2x32) ---
  s16x8 wifrag[NT];
  if (wave < 2) {
#pragma unroll
    for (int nt = 0; nt < NT; ++nt) {
      const float4* q = (const float4*)(Wi + (size_t)(colbase + nt * 16 + l15) * NIN_ + wave * 32 + koct * 8);
      wifrag[nt] = cvt8(q[0], q[1]);
    }
  }

  // thread (wave, lane) owns state element (batch = wave, col = lane)
  const int cc   = lane;
  const int bloc = wave;
  const int bg   = isl * MB + bloc;                 // global batch
  const int nn   = colbase + cc;                    // global col
  const int abatch = isl * MB + (l15 & 3);          // A-row batch (rows dup 4x)
  const int ub   = isl * MB + (l15 & 3);            // U-row batch

  // pointers
  const float* SNp = SN + (size_t)bg * T_ * N_ + nn;
  const float* RNp = RN + (size_t)bg * T_ * N_ + nn;
  float*       Xp  = X  + (size_t)bg * T_ * N_ + nn;
  float*       Rp  = R  + (size_t)bg * T_ * N_ + nn;
  const float* Up  = U  + (size_t)ub * T_ * NIN_ + wave * 32 + koct * 8;

  const int kbase_dw = (wave * KW + koct * 8) >> 1;
  const unsigned* ex0 = ex + (size_t)abatch * (N_ / 2) + kbase_dw;   // parity 0
  const unsigned* ex1 = ex0 + (size_t)B_ * (N_ / 2);                 // parity 1
  unsigned* exw0 = ex + (size_t)bg * (N_ / 2) + (nn >> 1);           // publish par 0
  unsigned* exw1 = exw0 + (size_t)B_ * (N_ / 2);                     // publish par 1

  const float x0v = X0[nn];
  const float bin = Bi[nn];
  float sn_c = SNp[0], rn_c = RNp[0];          // noise for t (prefetched 2-deep)
  float sn_n = SNp[N_], rn_n = RNp[N_];        // noise for t+1

  __shared__ float part[4][COLS][MB];          // [wave][col][batch^swz]

  // publish r_0 into parity-0 buffer with tag 0 (self-validating, no drain)
  {
    const float r0 = fmaxf(tanhf(x0v), 0.f);
    unsigned short h = f2bf(r0);
    unsigned other = __shfl_xor((unsigned)h, 1);
    if (!(lane & 1)) {
      unsigned vv = ((unsigned)h & ~1u) | (other << 16);   // tag bit = 0
      __hip_atomic_store(exw0, vv, __ATOMIC_RELAXED, __HIP_MEMORY_SCOPE_AGENT);
    }
  }

  float x = x0v;
  for (int t = 0; t < T_; ++t) {
    const unsigned tgm = ((t >> 1) & 1) ? 0xFFFFFFFFu : 0u;
    const unsigned* bp = (t & 1) ? ex1 : ex0;

    // current-step U load (waves 0,1): latency absorbed by first poll wait
    float4 uq0, uq1;
    if (wave < 2) {
      const float4* q = (const float4*)(Up + (size_t)t * NIN_);
      uq0 = q[0]; uq1 = q[1];
    }

    // ---- poll = tagged data load; retry until all 32 dwords carry tag t ----
    s16x8 afr[KT];
    LDALL();
    for (;;) {
      asm volatile("s_waitcnt vmcnt(0)" ::: "memory");
      unsigned bad = 0;
#pragma unroll
      for (int kt = 0; kt < KT; ++kt) {
        union { s16x8 v; unsigned u[4]; } w; w.v = afr[kt];
        bad |= (w.u[0] ^ tgm) | (w.u[1] ^ tgm) | (w.u[2] ^ tgm) | (w.u[3] ^ tgm);
      }
      if (__all((int)((bad & 1u) == 0u))) break;
      LDALL();
    }
    __builtin_amdgcn_sched_barrier(0);   // keep MFMA below the final wait

    // prefetch SN/RN for t+2 (2-deep: HBM latency fully off the chain)
    float sn2 = 0.f, rn2 = 0.f;
    if (t + 2 < T_) { sn2 = SNp[(size_t)(t + 2) * N_]; rn2 = RNp[(size_t)(t + 2) * N_]; }

    f32x4 acc[NT];
#pragma unroll
    for (int nt = 0; nt < NT; ++nt) acc[nt] = f32x4{0.f, 0.f, 0.f, 0.f};
#pragma unroll
    for (int kt = 0; kt < KT; ++kt)
#pragma unroll
      for (int nt = 0; nt < NT; ++nt)
        acc[nt] = __builtin_amdgcn_mfma_f32_16x16x32_bf16(afr[kt], bfrag[kt][nt], acc[nt], 0, 0, 0);
    if (wave < 2) {
      s16x8 ua = cvt8(uq0, uq1);
#pragma unroll
      for (int nt = 0; nt < NT; ++nt)
        acc[nt] = __builtin_amdgcn_mfma_f32_16x16x32_bf16(ua, wifrag[nt], acc[nt], 0, 0, 0);
    }

    // cross-wave K-partials; XOR-swizzle batch slot by (col>>3)&3 so the
    // stride-16B read spreads across all 32 banks (8-way -> 2-way = free)
    if (lane < 16) {
#pragma unroll
      for (int nt = 0; nt < NT; ++nt) {
        const int s = (nt * 2 + (lane >> 3)) & 3;
        f32x4 a = acc[nt];
        if (s & 1) a = f32x4{a[1], a[0], a[3], a[2]};
        if (s & 2) a = f32x4{a[2], a[3], a[0], a[1]};
        *(f32x4*)&part[wave][nt * 16 + lane][0] = a;   // slot j holds acc[j^s]
      }
    }
    __syncthreads();
    const int sr = (cc >> 3) & 3;
    const float mat = part[0][cc][bloc ^ sr] + part[1][cc][bloc ^ sr] +
                      part[2][cc][bloc ^ sr] + part[3][cc][bloc ^ sr];
    const float xn = x + 0.1f * (-x + mat + bin + sn_c);
    const float rv = fmaxf(tanhf(xn), 0.f) + rn_c;
    x = xn;

    // publish r_{t+1} into parity (t+1)&1 with tag ((t+1)>>1)&1 stamped into
    // bit 0 (low bf16 LSB only; <=1 ulp perturbation on even-indexed cols)
    {
      const unsigned tgn = ((t + 1) >> 1) & 1;
      unsigned short h = f2bf(rv);
      unsigned other = __shfl_xor((unsigned)h, 1);
      if (!(lane & 1)) {
        unsigned vv = (((unsigned)h & ~1u) | tgn) | (other << 16);
        __hip_atomic_store((t & 1) ? exw0 : exw1, vv,
                           __ATOMIC_RELAXED, __HIP_MEMORY_SCOPE_AGENT);
      }
    }
    // X/R stores off the critical path; acks absorbed by next poll's vmcnt(0)
    Xp[(size_t)t * N_] = xn;
    Rp[(size_t)t * N_] = rv;

    sn_c = sn_n; rn_c = rn_n; sn_n = sn2; rn_n = rn2;
  }
}

// ---------------------------------------------------------------------------
// Z = R @ W_out^T + b_out + output_noise.  W_out register-resident per thread
// (o = tid&31, kc = tid>>5 owns W_out[o][kc*128..+128)); R row staged in LDS.
// ---------------------------------------------------------------------------
#define TCH 128
__global__ __launch_bounds__(256, 1) void rnn_zout(
    const float* __restrict__ Rm, const float* __restrict__ ON,
    const float* __restrict__ Wo, const float* __restrict__ Bo,
    float* __restrict__ Z)
{
  const int bid = blockIdx.x;
  const int b = bid >> 2, tq = bid & 3;
  const int tid = threadIdx.x;
  const int o = tid & 31, kc = tid >> 5;

  float4 wv[32];
  const float4* wp = (const float4*)(Wo + (size_t)o * N_ + kc * 128);
#pragma unroll
  for (int i = 0; i < 32; ++i) wv[i] = wp[i];

  __shared__ float Rl[N_];
  __shared__ float zred[8][32];

  for (int t = tq * TCH; t < tq * TCH + TCH; ++t) {
    const size_t row = (size_t)b * T_ + t;
    ((float4*)Rl)[tid] = ((const float4*)(Rm + row * N_))[tid];
    __syncthreads();
    float a0 = 0.f;
#pragma unroll
    for (int i = 0; i < 32; ++i) {
      const float* rp = Rl + kc * 128 + i * 4;
      a0 += wv[i].x * rp[0] + wv[i].y * rp[1] + wv[i].z * rp[2] + wv[i].w * rp[3];
    }
    zred[kc][o] = a0;
    __syncthreads();
    if (tid < 32) {
      float z = Bo[tid];
#pragma unroll
      for (int k = 0; k < 8; ++k) z += zred[k][tid];
      Z[row * NOUT_ + tid] = z + ON[row * NOUT_ + tid];
    }
    // no 3rd barrier needed: zred(t+1) writes are gated by the next
    // post-stage __syncthreads, which the reducer reaches only after reading.
  }
}

extern "C" void kernel_launch(void* const* d_in, const int* in_sizes, int n_in,
                              void* d_out, int out_size, void* d_ws, size_t ws_size,
                              hipStream_t stream) {
  const float* U  = (const float*)d_in[0];
  const float* X0 = (const float*)d_in[1];
  const float* SN = (const float*)d_in[2];
  const float* RN = (const float*)d_in[3];
  const float* ON = (const float*)d_in[4];
  const float* Wi = (const float*)d_in[5];
  const float* Bi = (const float*)d_in[6];
  const float* Wr = (const float*)d_in[7];
  const float* Wo = (const float*)d_in[8];
  const float* Bo = (const float*)d_in[9];

  float* X = (float*)d_out;
  float* R = X + (size_t)B_ * T_ * N_;
  float* Z = R + (size_t)B_ * T_ * N_;

  unsigned* ex = (unsigned*)d_ws;    // [2][B_][N_/2] bf16x2, self-tagged

  // invalidate exchange every call: 0xFF => dword bit0 = 1 != expected tag 0
  // at t=0/1 (and kills cross-replay stale tags). Graph-capture-safe.
  hipMemsetAsync(ex, 0xFF, EX_WORDS * sizeof(unsigned), stream);

  hipLaunchKernelGGL(rnn_scan, dim3(NISL * BPI), dim3(256), 0, stream,
                     U, X0, SN, RN, Wi, Bi, Wr, X, R, ex);
  hipLaunchKernelGGL(rnn_zout, dim3(B_ * (T_ / TCH)), dim3(256), 0, stream,
                     R, ON, Wo, Bo, Z);
}

// Round 6
// 1868.755 us; speedup vs baseline: 1.0971x; 1.0971x over previous
//
#include <hip/hip_runtime.h>
#include <hip/hip_bf16.h>
#include <stdint.h>

#define B_    64
#define T_    512
#define NIN_  64
#define N_    1024
#define NOUT_ 32

// persistent-scan decomposition
#define NISL  16            // islands (independent batch groups)
#define BPI   16            // blocks per island (N-slices)
#define MB    4             // batches per island  = B_/NISL
#define COLS  64            // output cols per block = N_/BPI
#define NT    4             // 16-wide N tiles per block
#define KW    256           // K range per wave = N_/4
#define KT    8             // 32-wide K steps per wave

// ws layout (words): per-wave flag slots [NISL][64], then exchange buffers
#define CTRL_WORDS  (NISL * 64)
#define EX_BYTE_OFF 65536
#define EX_WORDS    (2 * B_ * (N_ / 2))   // two parity buffers of bf16x2 dwords

typedef float f32x4 __attribute__((ext_vector_type(4)));
typedef short s16x8 __attribute__((ext_vector_type(8)));

__device__ __forceinline__ unsigned short f2bf(float f) {
  union { float f; unsigned u; } v; v.f = f;
  unsigned r = v.u + 0x7FFFu + ((v.u >> 16) & 1u);   // RNE, no NaN in data
  return (unsigned short)(r >> 16);
}

__device__ __forceinline__ s16x8 cvt8(float4 a, float4 b) {
  s16x8 f;
  f[0] = (short)f2bf(a.x); f[1] = (short)f2bf(a.y);
  f[2] = (short)f2bf(a.z); f[3] = (short)f2bf(a.w);
  f[4] = (short)f2bf(b.x); f[5] = (short)f2bf(b.y);
  f[6] = (short)f2bf(b.z); f[7] = (short)f2bf(b.w);
  return f;
}

// PROVEN-LIVE encodings only (R2/R4): agent-relaxed wt stores (sc1) and
// system-scope sc0 sc1 loads. No sc0-only anything (R3/R5 deadlock cause).
__device__ __forceinline__ void st4_wt(unsigned* p, unsigned v) {
  __hip_atomic_store(p, v, __ATOMIC_RELAXED, __HIP_MEMORY_SCOPE_AGENT);
}
__device__ __forceinline__ unsigned ldflag(const unsigned* p) {
  unsigned r;
  asm volatile("global_load_dword %0, %1, off sc0 sc1\n\ts_waitcnt vmcnt(0)"
               : "=v"(r) : "v"(p) : "memory");
  return r;
}
#define LD16S(dst, base, OFF) \
  asm volatile("global_load_dwordx4 %0, %1, off offset:" #OFF " sc0 sc1" \
               : "=v"(dst) : "v"(base) : "memory")
#define LDALLS() do { \
  LD16S(afr[0], bp, 0);   LD16S(afr[1], bp, 64);  \
  LD16S(afr[2], bp, 128); LD16S(afr[3], bp, 192); \
  LD16S(afr[4], bp, 256); LD16S(afr[5], bp, 320); \
  LD16S(afr[6], bp, 384); LD16S(afr[7], bp, 448); } while (0)
#define TAGCHECK(okvar) do { \
  unsigned bad_ = 0; \
  _Pragma("unroll") \
  for (int kt_ = 0; kt_ < KT; ++kt_) { \
    union { s16x8 v; unsigned u[4]; } w_; w_.v = afr[kt_]; \
    bad_ |= (w_.u[0] ^ tgm) | (w_.u[1] ^ tgm) | (w_.u[2] ^ tgm) | (w_.u[3] ^ tgm); \
  } \
  okvar = __all((int)((bad_ & 1u) == 0u)); \
} while (0)

// ---------------------------------------------------------------------------
// Persistent scan: 256 blocks = 16 islands x 16 N-slices, W_rec resident in
// VGPRs. Exchange dwords are self-tagged (bit 0 = step tag, R4-proven) so
// correctness never depends on flags; flags (per-wave slot counters) are an
// efficiency device for cheap waiting. Per step: SPECULATIVE data load +
// tag check (hit = single IF$ RT, skips the flag RT entirely); on miss,
// coalesced 256B flag poll, then bounded reload. One __syncthreads/step;
// part[]-reuse and buffer-overwrite safety follow from data dependence
// (publish is data-dependent on all reads of the prior step).
// ---------------------------------------------------------------------------
__global__ __launch_bounds__(256, 1) void rnn_scan(
    const float* __restrict__ U, const float* __restrict__ X0,
    const float* __restrict__ SN, const float* __restrict__ RN,
    const float* __restrict__ Wi, const float* __restrict__ Bi,
    const float* __restrict__ Wr,
    float* __restrict__ X, float* __restrict__ R,
    unsigned* __restrict__ ws)
{
  const int bid   = blockIdx.x;
  const int isl   = bid & 15, slice = bid >> 4;
  const int tid   = threadIdx.x;
  const int wave  = tid >> 6, lane = tid & 63;
  const int l15   = lane & 15, koct = lane >> 4;
  const int colbase = slice * COLS;
  const int wid   = slice * 4 + wave;              // island-wave id 0..63

  unsigned* const fl = ws + isl * 64;
  unsigned* const ex = (unsigned*)((char*)ws + EX_BYTE_OFF);

  // --- resident B fragments of W_rec slice: B[k][n] = W_rec[col n][k] ---
  s16x8 bfrag[KT][NT];
#pragma unroll
  for (int kt = 0; kt < KT; ++kt) {
    const int k0 = wave * KW + kt * 32 + koct * 8;
#pragma unroll
    for (int nt = 0; nt < NT; ++nt) {
      const float4* q = (const float4*)(Wr + (size_t)(colbase + nt * 16 + l15) * N_ + k0);
      bfrag[kt][nt] = cvt8(q[0], q[1]);
    }
  }
  // --- W_in fragments: input term split across waves 0,1 (K=64 = 2x32) ---
  s16x8 wifrag[NT];
  if (wave < 2) {
#pragma unroll
    for (int nt = 0; nt < NT; ++nt) {
      const float4* q = (const float4*)(Wi + (size_t)(colbase + nt * 16 + l15) * NIN_ + wave * 32 + koct * 8);
      wifrag[nt] = cvt8(q[0], q[1]);
    }
  }

  // thread (wave, lane) owns state element (batch = wave, col = lane)
  const int cc   = lane;
  const int bloc = wave;
  const int bg   = isl * MB + bloc;                 // global batch
  const int nn   = colbase + cc;                    // global col
  const int abatch = isl * MB + (l15 & 3);          // A-row batch (rows dup 4x)
  const int ub   = isl * MB + (l15 & 3);            // U-row batch

  const float* SNp = SN + (size_t)bg * T_ * N_ + nn;
  const float* RNp = RN + (size_t)bg * T_ * N_ + nn;
  float*       Xp  = X  + (size_t)bg * T_ * N_ + nn;
  float*       Rp  = R  + (size_t)bg * T_ * N_ + nn;
  const float* Up  = U  + (size_t)ub * T_ * NIN_ + wave * 32 + koct * 8;

  const int kbase_dw = (wave * KW + koct * 8) >> 1;
  const unsigned* ex0 = ex + (size_t)abatch * (N_ / 2) + kbase_dw;   // parity 0
  const unsigned* ex1 = ex0 + (size_t)B_ * (N_ / 2);                 // parity 1
  unsigned* exw0 = ex + (size_t)bg * (N_ / 2) + (nn >> 1);           // publish par 0
  unsigned* exw1 = exw0 + (size_t)B_ * (N_ / 2);                     // publish par 1

  const float x0v = X0[nn];
  const float bin = Bi[nn];
  float sn_c = SNp[0], rn_c = RNp[0];          // noise for t (prefetched 2-deep)
  float sn_n = SNp[N_], rn_n = RNp[N_];        // noise for t+1
  float4 uc0, uc1;                             // U(t) (prefetched 1-deep)
  if (wave < 2) { const float4* q = (const float4*)Up; uc0 = q[0]; uc1 = q[1]; }

  __shared__ float part[4][COLS][MB];          // [wave][col][batch^swz]

  // publish r_0 (tag 0) + post slot 1 — no drain; tags cover the race
  {
    const float r0 = fmaxf(tanhf(x0v), 0.f);
    unsigned short h = f2bf(r0);
    unsigned other = __shfl_xor((unsigned)h, 1);
    if (!(lane & 1)) {
      unsigned vv = ((unsigned)h & ~1u) | (other << 16);
      st4_wt(exw0, vv);
    }
    if (lane == 0) st4_wt(fl + wid, 1u);
  }

  float x = x0v;
  for (int t = 0; t < T_; ++t) {
    const unsigned tgm = ((t >> 1) & 1) ? 0xFFFFFFFFu : 0u;
    const unsigned* bp = (t & 1) ? ex1 : ex0;

    // ---- speculative data load + tag check (hit = 1 IF$ RT, no flag RT) ----
    s16x8 afr[KT];
    int ok;
    LDALLS();
    asm volatile("s_waitcnt vmcnt(0)" ::: "memory");
    TAGCHECK(ok);
    if (!ok) {
      // flag gate: one coalesced 256B load/iter, lane L checks slot L
      const unsigned need = (unsigned)(t + 1);
      for (;;) {
        unsigned fv = ldflag(fl + lane);
        if (__all((int)(fv >= need))) break;
        __builtin_amdgcn_s_sleep(1);
      }
      // flags ready: bounded reload until tags clean (typically 1 pass)
      for (;;) {
        LDALLS();
        asm volatile("s_waitcnt vmcnt(0)" ::: "memory");
        TAGCHECK(ok);
        if (ok) break;
        __builtin_amdgcn_s_sleep(1);
      }
    }
    __builtin_amdgcn_sched_barrier(0);   // keep MFMA below the final wait

    // prefetch SN/RN for t+2 and U for t+1 (issued here, consumed next step;
    // their latency is covered by next step's speculative vmcnt(0))
    float sn2 = 0.f, rn2 = 0.f;
    if (t + 2 < T_) { sn2 = SNp[(size_t)(t + 2) * N_]; rn2 = RNp[(size_t)(t + 2) * N_]; }
    float4 un0 = uc0, un1 = uc1;
    if (wave < 2 && t + 1 < T_) {
      const float4* q = (const float4*)(Up + (size_t)(t + 1) * NIN_);
      un0 = q[0]; un1 = q[1];
    }

    f32x4 acc[NT];
#pragma unroll
    for (int nt = 0; nt < NT; ++nt) acc[nt] = f32x4{0.f, 0.f, 0.f, 0.f};
#pragma unroll
    for (int kt = 0; kt < KT; ++kt)
#pragma unroll
      for (int nt = 0; nt < NT; ++nt)
        acc[nt] = __builtin_amdgcn_mfma_f32_16x16x32_bf16(afr[kt], bfrag[kt][nt], acc[nt], 0, 0, 0);
    if (wave < 2) {
      s16x8 ua = cvt8(uc0, uc1);
#pragma unroll
      for (int nt = 0; nt < NT; ++nt)
        acc[nt] = __builtin_amdgcn_mfma_f32_16x16x32_bf16(ua, wifrag[nt], acc[nt], 0, 0, 0);
    }

    // cross-wave K-partials; batch-slot XOR swizzle (R4-proven: conflicts=0)
    if (lane < 16) {
#pragma unroll
      for (int nt = 0; nt < NT; ++nt) {
        const int s = (nt * 2 + (lane >> 3)) & 3;
        f32x4 a = acc[nt];
        if (s & 1) a = f32x4{a[1], a[0], a[3], a[2]};
        if (s & 2) a = f32x4{a[2], a[3], a[0], a[1]};
        *(f32x4*)&part[wave][nt * 16 + lane][0] = a;   // slot j holds acc[j^s]
      }
    }
    __syncthreads();
    const int sr = (cc >> 3) & 3;
    const float mat = part[0][cc][bloc ^ sr] + part[1][cc][bloc ^ sr] +
                      part[2][cc][bloc ^ sr] + part[3][cc][bloc ^ sr];
    const float xn = x + 0.1f * (-x + mat + bin + sn_c);
    const float rv = fmaxf(tanhf(xn), 0.f) + rn_c;
    x = xn;

    // publish r_{t+1} (tag ((t+1)>>1)&1 in bit 0) then post slot t+2 —
    // no drain between; consumer tag-retry covers the reorder window
    {
      const unsigned tgn = ((t + 1) >> 1) & 1;
      unsigned short h = f2bf(rv);
      unsigned other = __shfl_xor((unsigned)h, 1);
      if (!(lane & 1)) {
        unsigned vv = (((unsigned)h & ~1u) | tgn) | (other << 16);
        st4_wt((t & 1) ? exw0 : exw1, vv);
      }
      if (lane == 0) st4_wt(fl + wid, (unsigned)(t + 2));
    }
    // X/R stores off the sync path; acks absorbed by next step's vmcnt(0)
    Xp[(size_t)t * N_] = xn;
    Rp[(size_t)t * N_] = rv;

    sn_c = sn_n; rn_c = rn_n; sn_n = sn2; rn_n = rn2;
    uc0 = un0; uc1 = un1;
  }
}

// ---------------------------------------------------------------------------
// Z = R @ W_out^T + b_out + output_noise.  W_out register-resident; R rows
// double-buffered in LDS; one barrier per row; 512 blocks (2/CU).
// ---------------------------------------------------------------------------
#define TCH 64
__global__ __launch_bounds__(256, 2) void rnn_zout(
    const float* __restrict__ Rm, const float* __restrict__ ON,
    const float* __restrict__ Wo, const float* __restrict__ Bo,
    float* __restrict__ Z)
{
  const int bid = blockIdx.x;
  const int b = bid >> 3, tq = bid & 7;
  const int tid = threadIdx.x;
  const int o = tid & 31, kc = tid >> 5;

  float4 wv[32];
  const float4* wp = (const float4*)(Wo + (size_t)o * N_ + kc * 128);
#pragma unroll
  for (int i = 0; i < 32; ++i) wv[i] = wp[i];
  const float bo = Bo[o];

  __shared__ float Rl[2][N_];
  __shared__ float zred[2][8][32];

  const int t0 = tq * TCH;
  ((float4*)Rl[0])[tid] = ((const float4*)(Rm + ((size_t)b * T_ + t0) * N_))[tid];
  __syncthreads();

  for (int i = 0; i < TCH; ++i) {
    const int cur = i & 1;
    const size_t row = (size_t)b * T_ + t0 + i;
    float4 nx;
    if (i + 1 < TCH)
      nx = ((const float4*)(Rm + (row + 1) * N_))[tid];
    float a0 = 0.f;
#pragma unroll
    for (int j = 0; j < 32; ++j) {
      const float* rp = &Rl[cur][kc * 128 + j * 4];
      a0 += wv[j].x * rp[0] + wv[j].y * rp[1] + wv[j].z * rp[2] + wv[j].w * rp[3];
    }
    if (i + 1 < TCH)
      ((float4*)Rl[cur ^ 1])[tid] = nx;
    zred[cur][kc][o] = a0;
    __syncthreads();
    if (tid < 32) {
      float z = bo;
#pragma unroll
      for (int k = 0; k < 8; ++k) z += zred[cur][k][tid];
      Z[row * NOUT_ + tid] = z + ON[row * NOUT_ + tid];
    }
    // reduce(i) reads zred[cur] after barrier(i); the next write to the same
    // zred/Rl buffer happens only after barrier(i+1) gates it. Race-free.
  }
}

extern "C" void kernel_launch(void* const* d_in, const int* in_sizes, int n_in,
                              void* d_out, int out_size, void* d_ws, size_t ws_size,
                              hipStream_t stream) {
  const float* U  = (const float*)d_in[0];
  const float* X0 = (const float*)d_in[1];
  const float* SN = (const float*)d_in[2];
  const float* RN = (const float*)d_in[3];
  const float* ON = (const float*)d_in[4];
  const float* Wi = (const float*)d_in[5];
  const float* Bi = (const float*)d_in[6];
  const float* Wr = (const float*)d_in[7];
  const float* Wo = (const float*)d_in[8];
  const float* Bo = (const float*)d_in[9];

  float* X = (float*)d_out;
  float* R = X + (size_t)B_ * T_ * N_;
  float* Z = R + (size_t)B_ * T_ * N_;

  unsigned* ws = (unsigned*)d_ws;
  unsigned* ex = (unsigned*)((char*)d_ws + EX_BYTE_OFF);

  // zero flag slots; invalidate exchange tags (0xFF => bit0=1 = stale at
  // t=0, and kills cross-replay stale tags). Graph-capture-safe.
  hipMemsetAsync(ws, 0, CTRL_WORDS * sizeof(unsigned), stream);
  hipMemsetAsync(ex, 0xFF, EX_WORDS * sizeof(unsigned), stream);

  hipLaunchKernelGGL(rnn_scan, dim3(NISL * BPI), dim3(256), 0, stream,
                     U, X0, SN, RN, Wi, Bi, Wr, X, R, ws);
  hipLaunchKernelGGL(rnn_zout, dim3(B_ * (T_ / TCH)), dim3(256), 0, stream,
                     R, ON, Wo, Bo, Z);
}

// Round 7
// 1776.040 us; speedup vs baseline: 1.1544x; 1.0522x over previous
//
#include <hip/hip_runtime.h>
#include <hip/hip_bf16.h>
#include <stdint.h>

#define B_    64
#define T_    512
#define NIN_  64
#define N_    1024
#define NOUT_ 32

// persistent-scan decomposition
#define NISL  16            // islands (independent batch groups)
#define BPI   16            // blocks per island (N-slices)
#define MB    4             // batches per island  = B_/NISL
#define COLS  64            // output cols per block = N_/BPI
#define NT    4             // 16-wide N tiles per block
#define KW    256           // K range per wave = N_/4
#define KT    8             // 32-wide K steps per wave

// ws layout (words): per-wave flag slots [NISL][64], then exchange buffers
#define CTRL_WORDS  (NISL * 64)
#define EX_BYTE_OFF 65536
#define EX_WORDS    (2 * B_ * (N_ / 2))   // two parity buffers of bf16x2 dwords

typedef float f32x4 __attribute__((ext_vector_type(4)));
typedef short s16x8 __attribute__((ext_vector_type(8)));

__device__ __forceinline__ unsigned short f2bf(float f) {
  union { float f; unsigned u; } v; v.f = f;
  unsigned r = v.u + 0x7FFFu + ((v.u >> 16) & 1u);   // RNE, no NaN in data
  return (unsigned short)(r >> 16);
}

__device__ __forceinline__ s16x8 cvt8(float4 a, float4 b) {
  s16x8 f;
  f[0] = (short)f2bf(a.x); f[1] = (short)f2bf(a.y);
  f[2] = (short)f2bf(a.z); f[3] = (short)f2bf(a.w);
  f[4] = (short)f2bf(b.x); f[5] = (short)f2bf(b.y);
  f[6] = (short)f2bf(b.z); f[7] = (short)f2bf(b.w);
  return f;
}

// PROVEN-LIVE encodings only (R2/R4/R6): agent-relaxed wt stores (sc1) and
// system-scope sc0 sc1 loads. No sc0-only anything (R3/R5 deadlock cause).
__device__ __forceinline__ void st4_wt(unsigned* p, unsigned v) {
  __hip_atomic_store(p, v, __ATOMIC_RELAXED, __HIP_MEMORY_SCOPE_AGENT);
}
__device__ __forceinline__ unsigned ldflag(const unsigned* p) {
  unsigned r;
  asm volatile("global_load_dword %0, %1, off sc0 sc1\n\ts_waitcnt vmcnt(0)"
               : "=v"(r) : "v"(p) : "memory");
  return r;
}
#define LD16S(dst, base, OFF) \
  asm volatile("global_load_dwordx4 %0, %1, off offset:" #OFF " sc0 sc1" \
               : "=v"(dst) : "v"(base) : "memory")
#define LDALLS() do { \
  LD16S(afr[0], bp, 0);   LD16S(afr[1], bp, 64);  \
  LD16S(afr[2], bp, 128); LD16S(afr[3], bp, 192); \
  LD16S(afr[4], bp, 256); LD16S(afr[5], bp, 320); \
  LD16S(afr[6], bp, 384); LD16S(afr[7], bp, 448); } while (0)
#define TAGCHECK(okvar) do { \
  unsigned bad_ = 0; \
  _Pragma("unroll") \
  for (int kt_ = 0; kt_ < KT; ++kt_) { \
    union { s16x8 v; unsigned u[4]; } w_; w_.v = afr[kt_]; \
    bad_ |= (w_.u[0] ^ tgm) | (w_.u[1] ^ tgm) | (w_.u[2] ^ tgm) | (w_.u[3] ^ tgm); \
  } \
  okvar = __all((int)((bad_ & 1u) == 0u)); \
} while (0)

// ---------------------------------------------------------------------------
// Persistent scan ("R2.5"): 256 blocks = 16 islands x 16 N-slices, W_rec
// resident in VGPRs. Protocol per step:
//   poll 64 per-wave flag slots (coalesced 256B sc0sc1 load, no RMWs)
//   -> load 8KB r-data (sc0sc1; bit-0 step tags as safety net)
//   -> MFMA -> part[] LDS exchange (ONE barrier) -> state update
//   -> publish r stores (wt) -> vmcnt(0) drain -> post own slot (wt)
//   -> only then X/R stores + SN/RN/U prefetches (so the drain never waits
//      on HBM traffic; they complete during the next step's poll).
// Ordering: data-before-flag via the drain (R2-proven). part[] reuse across
// steps is gated by the flag protocol (slot>=t+2 is data-dependent on that
// wave's part-read of step t). Tags cover any residual window.
// ---------------------------------------------------------------------------
__global__ __launch_bounds__(256, 1) void rnn_scan(
    const float* __restrict__ U, const float* __restrict__ X0,
    const float* __restrict__ SN, const float* __restrict__ RN,
    const float* __restrict__ Wi, const float* __restrict__ Bi,
    const float* __restrict__ Wr,
    float* __restrict__ X, float* __restrict__ R,
    unsigned* __restrict__ ws)
{
  const int bid   = blockIdx.x;
  const int isl   = bid & 15, slice = bid >> 4;
  const int tid   = threadIdx.x;
  const int wave  = tid >> 6, lane = tid & 63;
  const int l15   = lane & 15, koct = lane >> 4;
  const int colbase = slice * COLS;
  const int wid   = slice * 4 + wave;              // island-wave id 0..63

  unsigned* const fl = ws + isl * 64;
  unsigned* const ex = (unsigned*)((char*)ws + EX_BYTE_OFF);

  // --- resident B fragments of W_rec slice: B[k][n] = W_rec[col n][k] ---
  s16x8 bfrag[KT][NT];
#pragma unroll
  for (int kt = 0; kt < KT; ++kt) {
    const int k0 = wave * KW + kt * 32 + koct * 8;
#pragma unroll
    for (int nt = 0; nt < NT; ++nt) {
      const float4* q = (const float4*)(Wr + (size_t)(colbase + nt * 16 + l15) * N_ + k0);
      bfrag[kt][nt] = cvt8(q[0], q[1]);
    }
  }
  // --- W_in fragments: input term split across waves 0,1 (K=64 = 2x32) ---
  s16x8 wifrag[NT];
  if (wave < 2) {
#pragma unroll
    for (int nt = 0; nt < NT; ++nt) {
      const float4* q = (const float4*)(Wi + (size_t)(colbase + nt * 16 + l15) * NIN_ + wave * 32 + koct * 8);
      wifrag[nt] = cvt8(q[0], q[1]);
    }
  }

  // thread (wave, lane) owns state element (batch = wave, col = lane)
  const int cc   = lane;
  const int bloc = wave;
  const int bg   = isl * MB + bloc;                 // global batch
  const int nn   = colbase + cc;                    // global col
  const int abatch = isl * MB + (l15 & 3);          // A-row batch (rows dup 4x)
  const int ub   = isl * MB + (l15 & 3);            // U-row batch

  const float* SNp = SN + (size_t)bg * T_ * N_ + nn;
  const float* RNp = RN + (size_t)bg * T_ * N_ + nn;
  float*       Xp  = X  + (size_t)bg * T_ * N_ + nn;
  float*       Rp  = R  + (size_t)bg * T_ * N_ + nn;
  const float* Up  = U  + (size_t)ub * T_ * NIN_ + wave * 32 + koct * 8;

  const int kbase_dw = (wave * KW + koct * 8) >> 1;
  const unsigned* ex0 = ex + (size_t)abatch * (N_ / 2) + kbase_dw;   // parity 0
  const unsigned* ex1 = ex0 + (size_t)B_ * (N_ / 2);                 // parity 1
  unsigned* exw0 = ex + (size_t)bg * (N_ / 2) + (nn >> 1);           // publish par 0
  unsigned* exw1 = exw0 + (size_t)B_ * (N_ / 2);                     // publish par 1

  const float x0v = X0[nn];
  const float bin = Bi[nn];

  __shared__ float part[4][COLS][MB];          // [wave][col][batch^swz]

  // ---- prologue: publish r_0 (tag 0), drain, post slot 1, then prefetch ----
  {
    const float r0 = fmaxf(tanhf(x0v), 0.f);
    unsigned short h = f2bf(r0);
    unsigned other = __shfl_xor((unsigned)h, 1);
    if (!(lane & 1)) {
      unsigned vv = ((unsigned)h & ~1u) | (other << 16);
      st4_wt(exw0, vv);
    }
    asm volatile("s_waitcnt vmcnt(0)" ::: "memory");   // data before flag
    if (lane == 0) st4_wt(fl + wid, 1u);
  }
  float sn_c = SNp[0], rn_c = RNp[0];          // noise for t (2-deep prefetch)
  float sn_n = SNp[N_], rn_n = RNp[N_];        // noise for t+1
  float4 uc0, uc1;                             // U(t) (1-deep prefetch)
  if (wave < 2) { const float4* q = (const float4*)Up; uc0 = q[0]; uc1 = q[1]; }

  float x = x0v;
  for (int t = 0; t < T_; ++t) {
    const unsigned tgm = ((t >> 1) & 1) ? 0xFFFFFFFFu : 0u;
    const unsigned* bp = (t & 1) ? ex1 : ex0;

    // ---- 1. flag gate: one coalesced 256B load/pass, lane L checks slot L ----
    {
      const unsigned need = (unsigned)(t + 1);
      for (;;) {
        unsigned fv = ldflag(fl + lane);
        if (__all((int)(fv >= need))) break;
        __builtin_amdgcn_s_sleep(1);
      }
    }

    // ---- 2. data load (first pass should be clean: drain-before-flag) ----
    s16x8 afr[KT];
    int ok;
    LDALLS();
    asm volatile("s_waitcnt vmcnt(0)" ::: "memory");
    TAGCHECK(ok);
    while (!ok) {
      __builtin_amdgcn_s_sleep(1);
      LDALLS();
      asm volatile("s_waitcnt vmcnt(0)" ::: "memory");
      TAGCHECK(ok);
    }
    __builtin_amdgcn_sched_barrier(0);   // keep MFMA below the final wait

    // ---- 3. MFMA ----
    f32x4 acc[NT];
#pragma unroll
    for (int nt = 0; nt < NT; ++nt) acc[nt] = f32x4{0.f, 0.f, 0.f, 0.f};
#pragma unroll
    for (int kt = 0; kt < KT; ++kt)
#pragma unroll
      for (int nt = 0; nt < NT; ++nt)
        acc[nt] = __builtin_amdgcn_mfma_f32_16x16x32_bf16(afr[kt], bfrag[kt][nt], acc[nt], 0, 0, 0);
    if (wave < 2) {
      s16x8 ua = cvt8(uc0, uc1);
#pragma unroll
      for (int nt = 0; nt < NT; ++nt)
        acc[nt] = __builtin_amdgcn_mfma_f32_16x16x32_bf16(ua, wifrag[nt], acc[nt], 0, 0, 0);
    }

    // ---- 4. cross-wave K-partials (swizzled, conflict-free) + state ----
    if (lane < 16) {
#pragma unroll
      for (int nt = 0; nt < NT; ++nt) {
        const int s = (nt * 2 + (lane >> 3)) & 3;
        f32x4 a = acc[nt];
        if (s & 1) a = f32x4{a[1], a[0], a[3], a[2]};
        if (s & 2) a = f32x4{a[2], a[3], a[0], a[1]};
        *(f32x4*)&part[wave][nt * 16 + lane][0] = a;   // slot j holds acc[j^s]
      }
    }
    __syncthreads();
    const int sr = (cc >> 3) & 3;
    const float mat = part[0][cc][bloc ^ sr] + part[1][cc][bloc ^ sr] +
                      part[2][cc][bloc ^ sr] + part[3][cc][bloc ^ sr];
    const float xn = x + 0.1f * (-x + mat + bin + sn_c);
    const float rv = fmaxf(tanhf(xn), 0.f) + rn_c;
    x = xn;

    // ---- 5. publish r_{t+1} -> drain -> post slot (data-before-flag) ----
    {
      const unsigned tgn = ((t + 1) >> 1) & 1;
      unsigned short h = f2bf(rv);
      unsigned other = __shfl_xor((unsigned)h, 1);
      if (!(lane & 1)) {
        unsigned vv = (((unsigned)h & ~1u) | tgn) | (other << 16);
        st4_wt((t & 1) ? exw0 : exw1, vv);
      }
      // only the publish stores are outstanding here (X/R/prefetch from the
      // previous step completed during this step's poll) -> drain is 1 RT
      asm volatile("s_waitcnt vmcnt(0)" ::: "memory");
      if (lane == 0) st4_wt(fl + wid, (unsigned)(t + 2));
    }

    // ---- 6. off-chain traffic: X/R stores + next-step prefetches ----
    Xp[(size_t)t * N_] = xn;
    Rp[(size_t)t * N_] = rv;
    float sn2 = 0.f, rn2 = 0.f;
    if (t + 2 < T_) { sn2 = SNp[(size_t)(t + 2) * N_]; rn2 = RNp[(size_t)(t + 2) * N_]; }
    if (wave < 2 && t + 1 < T_) {
      const float4* q = (const float4*)(Up + (size_t)(t + 1) * NIN_);
      uc0 = q[0]; uc1 = q[1];
    }
    sn_c = sn_n; rn_c = rn_n; sn_n = sn2; rn_n = rn2;
  }
}

// ---------------------------------------------------------------------------
// Z = R @ W_out^T + b_out + output_noise.  W_out register-resident; R rows
// double-buffered in LDS; one barrier per row; 512 blocks (2/CU).
// ---------------------------------------------------------------------------
#define TCH 64
__global__ __launch_bounds__(256, 2) void rnn_zout(
    const float* __restrict__ Rm, const float* __restrict__ ON,
    const float* __restrict__ Wo, const float* __restrict__ Bo,
    float* __restrict__ Z)
{
  const int bid = blockIdx.x;
  const int b = bid >> 3, tq = bid & 7;
  const int tid = threadIdx.x;
  const int o = tid & 31, kc = tid >> 5;

  float4 wv[32];
  const float4* wp = (const float4*)(Wo + (size_t)o * N_ + kc * 128);
#pragma unroll
  for (int i = 0; i < 32; ++i) wv[i] = wp[i];
  const float bo = Bo[o];

  __shared__ float Rl[2][N_];
  __shared__ float zred[2][8][32];

  const int t0 = tq * TCH;
  ((float4*)Rl[0])[tid] = ((const float4*)(Rm + ((size_t)b * T_ + t0) * N_))[tid];
  __syncthreads();

  for (int i = 0; i < TCH; ++i) {
    const int cur = i & 1;
    const size_t row = (size_t)b * T_ + t0 + i;
    float4 nx;
    if (i + 1 < TCH)
      nx = ((const float4*)(Rm + (row + 1) * N_))[tid];
    float a0 = 0.f;
#pragma unroll
    for (int j = 0; j < 32; ++j) {
      const float* rp = &Rl[cur][kc * 128 + j * 4];
      a0 += wv[j].x * rp[0] + wv[j].y * rp[1] + wv[j].z * rp[2] + wv[j].w * rp[3];
    }
    if (i + 1 < TCH)
      ((float4*)Rl[cur ^ 1])[tid] = nx;
    zred[cur][kc][o] = a0;
    __syncthreads();
    if (tid < 32) {
      float z = bo;
#pragma unroll
      for (int k = 0; k < 8; ++k) z += zred[cur][k][tid];
      Z[row * NOUT_ + tid] = z + ON[row * NOUT_ + tid];
    }
    // reduce(i) reads zred[cur] after barrier(i); the next write to the same
    // zred/Rl buffer happens only after barrier(i+1) gates it. Race-free.
  }
}

extern "C" void kernel_launch(void* const* d_in, const int* in_sizes, int n_in,
                              void* d_out, int out_size, void* d_ws, size_t ws_size,
                              hipStream_t stream) {
  const float* U  = (const float*)d_in[0];
  const float* X0 = (const float*)d_in[1];
  const float* SN = (const float*)d_in[2];
  const float* RN = (const float*)d_in[3];
  const float* ON = (const float*)d_in[4];
  const float* Wi = (const float*)d_in[5];
  const float* Bi = (const float*)d_in[6];
  const float* Wr = (const float*)d_in[7];
  const float* Wo = (const float*)d_in[8];
  const float* Bo = (const float*)d_in[9];

  float* X = (float*)d_out;
  float* R = X + (size_t)B_ * T_ * N_;
  float* Z = R + (size_t)B_ * T_ * N_;

  unsigned* ws = (unsigned*)d_ws;
  unsigned* ex = (unsigned*)((char*)d_ws + EX_BYTE_OFF);

  // zero flag slots; invalidate exchange tags (0xFF => bit0=1 = stale at
  // t=0, and kills cross-replay stale tags). Graph-capture-safe.
  hipMemsetAsync(ws, 0, CTRL_WORDS * sizeof(unsigned), stream);
  hipMemsetAsync(ex, 0xFF, EX_WORDS * sizeof(unsigned), stream);

  hipLaunchKernelGGL(rnn_scan, dim3(NISL * BPI), dim3(256), 0, stream,
                     U, X0, SN, RN, Wi, Bi, Wr, X, R, ws);
  hipLaunchKernelGGL(rnn_zout, dim3(B_ * (T_ / TCH)), dim3(256), 0, stream,
                     R, ON, Wo, Bo, Z);
}

// Round 11
// 1628.897 us; speedup vs baseline: 1.2587x; 1.0903x over previous
//
#include <hip/hip_runtime.h>
#include <hip/hip_bf16.h>
#include <stdint.h>

#define B_    64
#define T_    512
#define NIN_  64
#define N_    1024
#define NOUT_ 32

// persistent-scan decomposition (R2 geometry, verbatim)
#define NISL  16            // islands (independent batch groups)
#define BPI   16            // blocks per island (N-slices)
#define MB    4             // batches per island  = B_/NISL
#define COLS  64            // output cols per block = N_/BPI
#define NT    4             // 16-wide N tiles per block
#define KW    256           // K range per wave = N_/4
#define KT    8             // 32-wide K steps per wave

typedef float f32x4 __attribute__((ext_vector_type(4)));
typedef short s16x8 __attribute__((ext_vector_type(8)));

__device__ __forceinline__ unsigned short f2bf(float f) {
  union { float f; unsigned u; } v; v.f = f;
  unsigned r = v.u + 0x7FFFu + ((v.u >> 16) & 1u);   // RNE, no NaN in data
  return (unsigned short)(r >> 16);
}

__device__ __forceinline__ s16x8 cvt8(float4 a, float4 b) {
  s16x8 f;
  f[0] = (short)f2bf(a.x); f[1] = (short)f2bf(a.y);
  f[2] = (short)f2bf(a.z); f[3] = (short)f2bf(a.w);
  f[4] = (short)f2bf(b.x); f[5] = (short)f2bf(b.y);
  f[6] = (short)f2bf(b.z); f[7] = (short)f2bf(b.w);
  return f;
}

__device__ __forceinline__ s16x8 pack4(unsigned a, unsigned b, unsigned c, unsigned d) {
  union { unsigned u[4]; s16x8 v; } x;
  x.u[0] = a; x.u[1] = b; x.u[2] = c; x.u[3] = d;
  return x.v;
}

// ---------------------------------------------------------------------------
// Persistent scan — R2's kernel VERBATIM (the only protocol measured live at
// 2.67us/step: all-thread relaxed-agent poll, compiler-atomic exchange
// loads/stores, publish -> __syncthreads drain -> tid0 fetch_add post,
// deferred X/R stores). NO inline asm anywhere in this kernel.
// Only protocol-neutral deltas vs R2:
//   * part[] XOR-swizzle layout (R4-proven: conflicts 12.6M -> 0; strictly
//     between two intra-block barriers, zero sync interaction)
//   * W prologue loads via float4+cvt8 (pre-protocol, R4/R6/R7-proven)
//   * U loads as float4, converted after the poll
// ---------------------------------------------------------------------------
__global__ __launch_bounds__(256, 1) void rnn_scan(
    const float* __restrict__ U, const float* __restrict__ X0,
    const float* __restrict__ SN, const float* __restrict__ RN,
    const float* __restrict__ Wi, const float* __restrict__ Bi,
    const float* __restrict__ Wr,
    float* __restrict__ X, float* __restrict__ R,
    unsigned* __restrict__ flags, unsigned* __restrict__ ex)
{
  const int bid   = blockIdx.x;
  const int isl   = bid / BPI, slice = bid % BPI;
  const int tid   = threadIdx.x;
  const int wave  = tid >> 6, lane = tid & 63;
  const int l15   = lane & 15, koct = lane >> 4;
  const int colbase = slice * COLS;

  // --- resident B fragments of W_rec slice: B[k][n] = W_rec[col n][k] ---
  s16x8 bfrag[KT][NT];
#pragma unroll
  for (int kt = 0; kt < KT; ++kt) {
    const int k0 = wave * KW + kt * 32 + koct * 8;
#pragma unroll
    for (int nt = 0; nt < NT; ++nt) {
      const float4* q = (const float4*)(Wr + (size_t)(colbase + nt * 16 + l15) * N_ + k0);
      bfrag[kt][nt] = cvt8(q[0], q[1]);
    }
  }
  // --- W_in fragments: input term split across waves 0,1 (K=64 = 2x32) ---
  s16x8 wifrag[NT];
  if (wave < 2) {
#pragma unroll
    for (int nt = 0; nt < NT; ++nt) {
      const float4* q = (const float4*)(Wi + (size_t)(colbase + nt * 16 + l15) * NIN_ + wave * 32 + koct * 8);
      wifrag[nt] = cvt8(q[0], q[1]);
    }
  }

  // thread (wave, lane) owns state element (batch = wave, col = lane)
  const int cc   = lane;
  const int bloc = wave;
  const int bg   = isl * MB + bloc;                 // global batch
  const int nn   = colbase + cc;                    // global col
  const int abatch = isl * MB + (l15 & 3);          // A-row batch (rows dup 4x)

  float x = X0[nn];
  const float bin = Bi[nn];
  const float r0 = fmaxf(tanhf(x), 0.f);

  __shared__ float part[4][COLS][MB];               // [wave][col][batch^swz]

  unsigned* const myflags = flags + isl * (T_ + 1);

  // publish r_0 into parity-0 exchange buffer (compiler wt atomics)
  {
    unsigned short h = f2bf(r0);
    unsigned other = __shfl_xor((unsigned)h, 1);
    if ((lane & 1) == 0)
      __hip_atomic_store(ex + (size_t)bg * (N_ / 2) + (nn >> 1),
                         (unsigned)h | (other << 16),
                         __ATOMIC_RELAXED, __HIP_MEMORY_SCOPE_AGENT);
  }
  __syncthreads();   // drains vmcnt for all waves -> ex visible before flag
  if (tid == 0)
    __hip_atomic_fetch_add(myflags, 1u, __ATOMIC_RELAXED, __HIP_MEMORY_SCOPE_AGENT);

  float pxn = 0.f, prv = 0.f;                      // deferred X/R store values

  for (int t = 0; t < T_; ++t) {
    const int par = t & 1;
    const size_t row = (size_t)bg * T_ + t;

    // independent loads issued before the wait (latency hides under spin)
    const float snv = SN[row * N_ + nn];
    const float rnv = RN[row * N_ + nn];
    float4 uq0, uq1;
    if (wave < 2) {
      const float4* q = (const float4*)(U + ((size_t)(isl * MB + (l15 & 3)) * T_ + t) * NIN_
                                          + wave * 32 + koct * 8);
      uq0 = q[0]; uq1 = q[1];
    }

    // all-thread relaxed poll (R2 verbatim)
    while (__hip_atomic_load(myflags + t, __ATOMIC_RELAXED, __HIP_MEMORY_SCOPE_AGENT) < BPI)
      __builtin_amdgcn_s_sleep(2);

    // previous step's X/R stores: issued here so their HBM ack overlaps the
    // exchange-load latency instead of sitting on the drain (R2 verbatim)
    if (t > 0) {
      X[(row - 1) * N_ + nn] = pxn;
      R[(row - 1) * N_ + nn] = prv;
    }

    // A fragments: compiler relaxed-agent loads from exchange buffer
    const unsigned* exr = ex + (size_t)par * (B_ * (N_ / 2))
                             + (size_t)abatch * (N_ / 2);
    s16x8 afr[KT];
#pragma unroll
    for (int kt = 0; kt < KT; ++kt) {
      const unsigned* p = exr + ((wave * KW + kt * 32 + koct * 8) >> 1);
      unsigned q0 = __hip_atomic_load(p + 0, __ATOMIC_RELAXED, __HIP_MEMORY_SCOPE_AGENT);
      unsigned q1 = __hip_atomic_load(p + 1, __ATOMIC_RELAXED, __HIP_MEMORY_SCOPE_AGENT);
      unsigned q2 = __hip_atomic_load(p + 2, __ATOMIC_RELAXED, __HIP_MEMORY_SCOPE_AGENT);
      unsigned q3 = __hip_atomic_load(p + 3, __ATOMIC_RELAXED, __HIP_MEMORY_SCOPE_AGENT);
      afr[kt] = pack4(q0, q1, q2, q3);
    }

    f32x4 acc[NT];
#pragma unroll
    for (int nt = 0; nt < NT; ++nt) acc[nt] = f32x4{0.f, 0.f, 0.f, 0.f};
#pragma unroll
    for (int kt = 0; kt < KT; ++kt)
#pragma unroll
      for (int nt = 0; nt < NT; ++nt)
        acc[nt] = __builtin_amdgcn_mfma_f32_16x16x32_bf16(afr[kt], bfrag[kt][nt], acc[nt], 0, 0, 0);
    if (wave < 2) {
      s16x8 ua = cvt8(uq0, uq1);
#pragma unroll
      for (int nt = 0; nt < NT; ++nt)
        acc[nt] = __builtin_amdgcn_mfma_f32_16x16x32_bf16(ua, wifrag[nt], acc[nt], 0, 0, 0);
    }

    // cross-wave K-partials; XOR-swizzled slot layout (R4-proven, conflict-0)
    if (lane < 16) {
#pragma unroll
      for (int nt = 0; nt < NT; ++nt) {
        const int s = (nt * 2 + (lane >> 3)) & 3;
        f32x4 a = acc[nt];
        if (s & 1) a = f32x4{a[1], a[0], a[3], a[2]};
        if (s & 2) a = f32x4{a[2], a[3], a[0], a[1]};
        *(f32x4*)&part[wave][nt * 16 + lane][0] = a;   // slot j holds acc[j^s]
      }
    }
    __syncthreads();
    const int sr = (cc >> 3) & 3;
    const float mat = part[0][cc][bloc ^ sr] + part[1][cc][bloc ^ sr] +
                      part[2][cc][bloc ^ sr] + part[3][cc][bloc ^ sr];
    const float xn = x + 0.1f * (-x + mat + bin + snv);
    const float rv = fmaxf(tanhf(xn), 0.f) + rnv;
    x = xn;

    // publish r_{t+1} (compiler wt atomics, R2 verbatim)
    {
      unsigned short h = f2bf(rv);
      unsigned other = __shfl_xor((unsigned)h, 1);
      if ((lane & 1) == 0)
        __hip_atomic_store(ex + (size_t)(par ^ 1) * (B_ * (N_ / 2)) +
                               (size_t)bg * (N_ / 2) + (nn >> 1),
                           (unsigned)h | (other << 16),
                           __ATOMIC_RELAXED, __HIP_MEMORY_SCOPE_AGENT);
    }
    __syncthreads();   // drains all waves' ex stores before the flag post
    if (tid == 0)
      __hip_atomic_fetch_add(myflags + t + 1, 1u, __ATOMIC_RELAXED, __HIP_MEMORY_SCOPE_AGENT);

    pxn = xn; prv = rv;
  }
  // final deferred store
  {
    const size_t lrow = (size_t)bg * T_ + (T_ - 1);
    X[lrow * N_ + nn] = pxn;
    R[lrow * N_ + nn] = prv;
  }
}

// ---------------------------------------------------------------------------
// Z = R @ W_out^T + b_out + output_noise.  W_out register-resident; R rows
// double-buffered in LDS; one barrier per row; 512 blocks (R6/R7-proven).
// ---------------------------------------------------------------------------
#define TCH 64
__global__ __launch_bounds__(256, 2) void rnn_zout(
    const float* __restrict__ Rm, const float* __restrict__ ON,
    const float* __restrict__ Wo, const float* __restrict__ Bo,
    float* __restrict__ Z)
{
  const int bid = blockIdx.x;
  const int b = bid >> 3, tq = bid & 7;
  const int tid = threadIdx.x;
  const int o = tid & 31, kc = tid >> 5;

  float4 wv[32];
  const float4* wp = (const float4*)(Wo + (size_t)o * N_ + kc * 128);
#pragma unroll
  for (int i = 0; i < 32; ++i) wv[i] = wp[i];
  const float bo = Bo[o];

  __shared__ float Rl[2][N_];
  __shared__ float zred[2][8][32];

  const int t0 = tq * TCH;
  ((float4*)Rl[0])[tid] = ((const float4*)(Rm + ((size_t)b * T_ + t0) * N_))[tid];
  __syncthreads();

  for (int i = 0; i < TCH; ++i) {
    const int cur = i & 1;
    const size_t row = (size_t)b * T_ + t0 + i;
    float4 nx;
    if (i + 1 < TCH)
      nx = ((const float4*)(Rm + (row + 1) * N_))[tid];
    float a0 = 0.f;
#pragma unroll
    for (int j = 0; j < 32; ++j) {
      const float* rp = &Rl[cur][kc * 128 + j * 4];
      a0 += wv[j].x * rp[0] + wv[j].y * rp[1] + wv[j].z * rp[2] + wv[j].w * rp[3];
    }
    if (i + 1 < TCH)
      ((float4*)Rl[cur ^ 1])[tid] = nx;
    zred[cur][kc][o] = a0;
    __syncthreads();
    if (tid < 32) {
      float z = bo;
#pragma unroll
      for (int k = 0; k < 8; ++k) z += zred[cur][k][tid];
      Z[row * NOUT_ + tid] = z + ON[row * NOUT_ + tid];
    }
    // reduce(i) reads zred[cur] after barrier(i); the next write to the same
    // zred/Rl buffer happens only after barrier(i+1) gates it. Race-free.
  }
}

extern "C" void kernel_launch(void* const* d_in, const int* in_sizes, int n_in,
                              void* d_out, int out_size, void* d_ws, size_t ws_size,
                              hipStream_t stream) {
  const float* U  = (const float*)d_in[0];
  const float* X0 = (const float*)d_in[1];
  const float* SN = (const float*)d_in[2];
  const float* RN = (const float*)d_in[3];
  const float* ON = (const float*)d_in[4];
  const float* Wi = (const float*)d_in[5];
  const float* Bi = (const float*)d_in[6];
  const float* Wr = (const float*)d_in[7];
  const float* Wo = (const float*)d_in[8];
  const float* Bo = (const float*)d_in[9];

  float* X = (float*)d_out;
  float* R = X + (size_t)B_ * T_ * N_;
  float* Z = R + (size_t)B_ * T_ * N_;

  unsigned* flags = (unsigned*)d_ws;                       // [NISL][T_+1]
  unsigned* ex    = (unsigned*)((char*)d_ws + 65536);      // [2][B_][N_/2] bf16x2

  // reset flags every call (graph-capture-safe; R2 verbatim)
  hipMemsetAsync(flags, 0, NISL * (T_ + 1) * sizeof(unsigned), stream);

  hipLaunchKernelGGL(rnn_scan, dim3(NISL * BPI), dim3(256), 0, stream,
                     U, X0, SN, RN, Wi, Bi, Wr, X, R, flags, ex);
  hipLaunchKernelGGL(rnn_zout, dim3(B_ * (T_ / TCH)), dim3(256), 0, stream,
                     R, ON, Wo, Bo, Z);
}

// Round 12
// 1533.040 us; speedup vs baseline: 1.3374x; 1.0625x over previous
//
#include <hip/hip_runtime.h>
#include <hip/hip_bf16.h>
#include <stdint.h>

#define B_    64
#define T_    512
#define NIN_  64
#define N_    1024
#define NOUT_ 32

// persistent-scan decomposition (R2/R11 geometry, verbatim)
#define NISL  16            // islands (independent batch groups)
#define BPI   16            // blocks per island (N-slices)
#define MB    4             // batches per island  = B_/NISL
#define COLS  64            // output cols per block = N_/BPI
#define NT    4             // 16-wide N tiles per block
#define KW    256           // K range per wave = N_/4
#define KT    8             // 32-wide K steps per wave

// mailbox matrix: mail[isl][consumer_slice][producer_slice] (16KB total).
// Consumer block (isl,c) polls its PRIVATE 64B line mail[isl][c][0..15];
// producer block (isl,p) posts step counters to the 16 lines at column p.
#define MAIL_WORDS (NISL * BPI * BPI)

typedef float f32x4 __attribute__((ext_vector_type(4)));
typedef short s16x8 __attribute__((ext_vector_type(8)));

__device__ __forceinline__ unsigned short f2bf(float f) {
  union { float f; unsigned u; } v; v.f = f;
  unsigned r = v.u + 0x7FFFu + ((v.u >> 16) & 1u);   // RNE, no NaN in data
  return (unsigned short)(r >> 16);
}

__device__ __forceinline__ s16x8 cvt8(float4 a, float4 b) {
  s16x8 f;
  f[0] = (short)f2bf(a.x); f[1] = (short)f2bf(a.y);
  f[2] = (short)f2bf(a.z); f[3] = (short)f2bf(a.w);
  f[4] = (short)f2bf(b.x); f[5] = (short)f2bf(b.y);
  f[6] = (short)f2bf(b.z); f[7] = (short)f2bf(b.w);
  return f;
}

__device__ __forceinline__ s16x8 pack4(unsigned a, unsigned b, unsigned c, unsigned d) {
  union { unsigned u[4]; s16x8 v; } x;
  x.u[0] = a; x.u[1] = b; x.u[2] = c; x.u[3] = d;
  return x.v;
}

// ---------------------------------------------------------------------------
// Persistent scan — R11's kernel (passed, scan 1556us) with ONE attributable
// change: the per-island single flag word (64 polling waves + 16 serialized
// RMWs on one IF$ line) is replaced by a consumer-private MAILBOX matrix:
//   post  = 16 plain relaxed-atomic stores (wave0 lanes<16, after B_drain,
//           same drain-before-post ordering as R2/R11)
//   poll  = each wave reads its block's own 64B line (lane&15 -> slot),
//           __all(slot >= t+1); per-wave, decoupled, same placement as R11.
// Readers per line: 64 waves -> 4; RMW eliminated. All primitives are
// compiler-generated relaxed agent atomics (the only class proven live).
// ---------------------------------------------------------------------------
__global__ __launch_bounds__(256, 1) void rnn_scan(
    const float* __restrict__ U, const float* __restrict__ X0,
    const float* __restrict__ SN, const float* __restrict__ RN,
    const float* __restrict__ Wi, const float* __restrict__ Bi,
    const float* __restrict__ Wr,
    float* __restrict__ X, float* __restrict__ R,
    unsigned* __restrict__ mail, unsigned* __restrict__ ex)
{
  const int bid   = blockIdx.x;
  const int isl   = bid / BPI, slice = bid % BPI;
  const int tid   = threadIdx.x;
  const int wave  = tid >> 6, lane = tid & 63;
  const int l15   = lane & 15, koct = lane >> 4;
  const int colbase = slice * COLS;

  // --- resident B fragments of W_rec slice: B[k][n] = W_rec[col n][k] ---
  s16x8 bfrag[KT][NT];
#pragma unroll
  for (int kt = 0; kt < KT; ++kt) {
    const int k0 = wave * KW + kt * 32 + koct * 8;
#pragma unroll
    for (int nt = 0; nt < NT; ++nt) {
      const float4* q = (const float4*)(Wr + (size_t)(colbase + nt * 16 + l15) * N_ + k0);
      bfrag[kt][nt] = cvt8(q[0], q[1]);
    }
  }
  // --- W_in fragments: input term split across waves 0,1 (K=64 = 2x32) ---
  s16x8 wifrag[NT];
  if (wave < 2) {
#pragma unroll
    for (int nt = 0; nt < NT; ++nt) {
      const float4* q = (const float4*)(Wi + (size_t)(colbase + nt * 16 + l15) * NIN_ + wave * 32 + koct * 8);
      wifrag[nt] = cvt8(q[0], q[1]);
    }
  }

  // thread (wave, lane) owns state element (batch = wave, col = lane)
  const int cc   = lane;
  const int bloc = wave;
  const int bg   = isl * MB + bloc;                 // global batch
  const int nn   = colbase + cc;                    // global col
  const int abatch = isl * MB + (l15 & 3);          // A-row batch (rows dup 4x)

  float x = X0[nn];
  const float bin = Bi[nn];
  const float r0 = fmaxf(tanhf(x), 0.f);

  __shared__ float part[4][COLS][MB];               // [wave][col][batch^swz]

  // consumer-private poll line; producer post column
  const unsigned* const myline = mail + (isl * BPI + slice) * BPI;  // 64B line
  unsigned* const postcol      = mail + isl * BPI * BPI + slice;    // +c*16

  // publish r_0 into parity-0 exchange buffer (compiler wt atomics)
  {
    unsigned short h = f2bf(r0);
    unsigned other = __shfl_xor((unsigned)h, 1);
    if ((lane & 1) == 0)
      __hip_atomic_store(ex + (size_t)bg * (N_ / 2) + (nn >> 1),
                         (unsigned)h | (other << 16),
                         __ATOMIC_RELAXED, __HIP_MEMORY_SCOPE_AGENT);
  }
  __syncthreads();   // drains vmcnt for all waves -> ex visible before post
  if (tid < BPI)     // wave0 lanes 0..15: one store per consumer block
    __hip_atomic_store(postcol + tid * BPI, 1u,
                       __ATOMIC_RELAXED, __HIP_MEMORY_SCOPE_AGENT);

  float pxn = 0.f, prv = 0.f;                      // deferred X/R store values

  for (int t = 0; t < T_; ++t) {
    const int par = t & 1;
    const size_t row = (size_t)bg * T_ + t;

    // independent loads issued before the wait (latency hides under spin)
    const float snv = SN[row * N_ + nn];
    const float rnv = RN[row * N_ + nn];
    float4 uq0, uq1;
    if (wave < 2) {
      const float4* q = (const float4*)(U + ((size_t)(isl * MB + (l15 & 3)) * T_ + t) * NIN_
                                          + wave * 32 + koct * 8);
      uq0 = q[0]; uq1 = q[1];
    }

    // per-wave mailbox poll: lane L checks producer slot L&15 on OUR line
    {
      const unsigned need = (unsigned)(t + 1);
      for (;;) {
        unsigned fv = __hip_atomic_load(myline + l15, __ATOMIC_RELAXED,
                                        __HIP_MEMORY_SCOPE_AGENT);
        if (__all((int)(fv >= need))) break;
        __builtin_amdgcn_s_sleep(2);
      }
    }

    // previous step's X/R stores: issued here so their HBM ack overlaps the
    // exchange-load latency (R2/R11 placement)
    if (t > 0) {
      X[(row - 1) * N_ + nn] = pxn;
      R[(row - 1) * N_ + nn] = prv;
    }

    // A fragments: compiler relaxed-agent loads from exchange buffer
    const unsigned* exr = ex + (size_t)par * (B_ * (N_ / 2))
                             + (size_t)abatch * (N_ / 2);
    s16x8 afr[KT];
#pragma unroll
    for (int kt = 0; kt < KT; ++kt) {
      const unsigned* p = exr + ((wave * KW + kt * 32 + koct * 8) >> 1);
      unsigned q0 = __hip_atomic_load(p + 0, __ATOMIC_RELAXED, __HIP_MEMORY_SCOPE_AGENT);
      unsigned q1 = __hip_atomic_load(p + 1, __ATOMIC_RELAXED, __HIP_MEMORY_SCOPE_AGENT);
      unsigned q2 = __hip_atomic_load(p + 2, __ATOMIC_RELAXED, __HIP_MEMORY_SCOPE_AGENT);
      unsigned q3 = __hip_atomic_load(p + 3, __ATOMIC_RELAXED, __HIP_MEMORY_SCOPE_AGENT);
      afr[kt] = pack4(q0, q1, q2, q3);
    }

    f32x4 acc[NT];
#pragma unroll
    for (int nt = 0; nt < NT; ++nt) acc[nt] = f32x4{0.f, 0.f, 0.f, 0.f};
#pragma unroll
    for (int kt = 0; kt < KT; ++kt)
#pragma unroll
      for (int nt = 0; nt < NT; ++nt)
        acc[nt] = __builtin_amdgcn_mfma_f32_16x16x32_bf16(afr[kt], bfrag[kt][nt], acc[nt], 0, 0, 0);
    if (wave < 2) {
      s16x8 ua = cvt8(uq0, uq1);
#pragma unroll
      for (int nt = 0; nt < NT; ++nt)
        acc[nt] = __builtin_amdgcn_mfma_f32_16x16x32_bf16(ua, wifrag[nt], acc[nt], 0, 0, 0);
    }

    // cross-wave K-partials; XOR-swizzled slot layout (R4-proven, conflict-0)
    if (lane < 16) {
#pragma unroll
      for (int nt = 0; nt < NT; ++nt) {
        const int s = (nt * 2 + (lane >> 3)) & 3;
        f32x4 a = acc[nt];
        if (s & 1) a = f32x4{a[1], a[0], a[3], a[2]};
        if (s & 2) a = f32x4{a[2], a[3], a[0], a[1]};
        *(f32x4*)&part[wave][nt * 16 + lane][0] = a;   // slot j holds acc[j^s]
      }
    }
    __syncthreads();
    const int sr = (cc >> 3) & 3;
    const float mat = part[0][cc][bloc ^ sr] + part[1][cc][bloc ^ sr] +
                      part[2][cc][bloc ^ sr] + part[3][cc][bloc ^ sr];
    const float xn = x + 0.1f * (-x + mat + bin + snv);
    const float rv = fmaxf(tanhf(xn), 0.f) + rnv;
    x = xn;

    // publish r_{t+1} (compiler wt atomics, R2/R11 verbatim)
    {
      unsigned short h = f2bf(rv);
      unsigned other = __shfl_xor((unsigned)h, 1);
      if ((lane & 1) == 0)
        __hip_atomic_store(ex + (size_t)(par ^ 1) * (B_ * (N_ / 2)) +
                               (size_t)bg * (N_ / 2) + (nn >> 1),
                           (unsigned)h | (other << 16),
                           __ATOMIC_RELAXED, __HIP_MEMORY_SCOPE_AGENT);
    }
    __syncthreads();   // B_drain: all waves' ex stores drained, then post
    if (tid < BPI)     // 16 mailbox stores to 16 consumer-private lines
      __hip_atomic_store(postcol + tid * BPI, (unsigned)(t + 2),
                         __ATOMIC_RELAXED, __HIP_MEMORY_SCOPE_AGENT);

    pxn = xn; prv = rv;
  }
  // final deferred store
  {
    const size_t lrow = (size_t)bg * T_ + (T_ - 1);
    X[lrow * N_ + nn] = pxn;
    R[lrow * N_ + nn] = prv;
  }
}

// ---------------------------------------------------------------------------
// Z = R @ W_out^T + b_out + output_noise.  W_out register-resident; R rows
// double-buffered in LDS; one barrier per row; 512 blocks (R6/R7/R11-proven).
// ---------------------------------------------------------------------------
#define TCH 64
__global__ __launch_bounds__(256, 2) void rnn_zout(
    const float* __restrict__ Rm, const float* __restrict__ ON,
    const float* __restrict__ Wo, const float* __restrict__ Bo,
    float* __restrict__ Z)
{
  const int bid = blockIdx.x;
  const int b = bid >> 3, tq = bid & 7;
  const int tid = threadIdx.x;
  const int o = tid & 31, kc = tid >> 5;

  float4 wv[32];
  const float4* wp = (const float4*)(Wo + (size_t)o * N_ + kc * 128);
#pragma unroll
  for (int i = 0; i < 32; ++i) wv[i] = wp[i];
  const float bo = Bo[o];

  __shared__ float Rl[2][N_];
  __shared__ float zred[2][8][32];

  const int t0 = tq * TCH;
  ((float4*)Rl[0])[tid] = ((const float4*)(Rm + ((size_t)b * T_ + t0) * N_))[tid];
  __syncthreads();

  for (int i = 0; i < TCH; ++i) {
    const int cur = i & 1;
    const size_t row = (size_t)b * T_ + t0 + i;
    float4 nx;
    if (i + 1 < TCH)
      nx = ((const float4*)(Rm + (row + 1) * N_))[tid];
    float a0 = 0.f;
#pragma unroll
    for (int j = 0; j < 32; ++j) {
      const float* rp = &Rl[cur][kc * 128 + j * 4];
      a0 += wv[j].x * rp[0] + wv[j].y * rp[1] + wv[j].z * rp[2] + wv[j].w * rp[3];
    }
    if (i + 1 < TCH)
      ((float4*)Rl[cur ^ 1])[tid] = nx;
    zred[cur][kc][o] = a0;
    __syncthreads();
    if (tid < 32) {
      float z = bo;
#pragma unroll
      for (int k = 0; k < 8; ++k) z += zred[cur][k][tid];
      Z[row * NOUT_ + tid] = z + ON[row * NOUT_ + tid];
    }
    // reduce(i) reads zred[cur] after barrier(i); the next write to the same
    // zred/Rl buffer happens only after barrier(i+1) gates it. Race-free.
  }
}

extern "C" void kernel_launch(void* const* d_in, const int* in_sizes, int n_in,
                              void* d_out, int out_size, void* d_ws, size_t ws_size,
                              hipStream_t stream) {
  const float* U  = (const float*)d_in[0];
  const float* X0 = (const float*)d_in[1];
  const float* SN = (const float*)d_in[2];
  const float* RN = (const float*)d_in[3];
  const float* ON = (const float*)d_in[4];
  const float* Wi = (const float*)d_in[5];
  const float* Bi = (const float*)d_in[6];
  const float* Wr = (const float*)d_in[7];
  const float* Wo = (const float*)d_in[8];
  const float* Bo = (const float*)d_in[9];

  float* X = (float*)d_out;
  float* R = X + (size_t)B_ * T_ * N_;
  float* Z = R + (size_t)B_ * T_ * N_;

  unsigned* mail = (unsigned*)d_ws;                        // [NISL][16][16]
  unsigned* ex   = (unsigned*)((char*)d_ws + 65536);       // [2][B_][N_/2] bf16x2

  // zero mailboxes every call (graph-capture-safe; 0 < first need of 1)
  hipMemsetAsync(mail, 0, MAIL_WORDS * sizeof(unsigned), stream);

  hipLaunchKernelGGL(rnn_scan, dim3(NISL * BPI), dim3(256), 0, stream,
                     U, X0, SN, RN, Wi, Bi, Wr, X, R, mail, ex);
  hipLaunchKernelGGL(rnn_zout, dim3(B_ * (T_ / TCH)), dim3(256), 0, stream,
                     R, ON, Wo, Bo, Z);
}

// Round 13
// 1519.056 us; speedup vs baseline: 1.3497x; 1.0092x over previous
//
#include <hip/hip_runtime.h>
#include <hip/hip_bf16.h>
#include <stdint.h>

#define B_    64
#define T_    512
#define NIN_  64
#define N_    1024
#define NOUT_ 32

// persistent-scan decomposition (R2/R11/R12 geometry, verbatim)
#define NISL  16            // islands (independent batch groups)
#define BPI   16            // blocks per island (N-slices)
#define MB    4             // batches per island  = B_/NISL
#define COLS  64            // output cols per block = N_/BPI
#define NT    4             // 16-wide N tiles per block
#define KW    256           // K range per wave = N_/4
#define KT    8             // 32-wide K steps per wave

// mailbox matrix: mail[isl][consumer_slice][producer_slice] (16KB total).
#define MAIL_WORDS (NISL * BPI * BPI)

typedef float f32x4 __attribute__((ext_vector_type(4)));
typedef short s16x8 __attribute__((ext_vector_type(8)));

__device__ __forceinline__ unsigned short f2bf(float f) {
  union { float f; unsigned u; } v; v.f = f;
  unsigned r = v.u + 0x7FFFu + ((v.u >> 16) & 1u);   // RNE, no NaN in data
  return (unsigned short)(r >> 16);
}

__device__ __forceinline__ s16x8 cvt8(float4 a, float4 b) {
  s16x8 f;
  f[0] = (short)f2bf(a.x); f[1] = (short)f2bf(a.y);
  f[2] = (short)f2bf(a.z); f[3] = (short)f2bf(a.w);
  f[4] = (short)f2bf(b.x); f[5] = (short)f2bf(b.y);
  f[6] = (short)f2bf(b.z); f[7] = (short)f2bf(b.w);
  return f;
}

// Vectorized exchange reads — EXACT R7-proven pattern (passed, correct):
// global_load_dwordx4 sc0 sc1 (coherence-point fresh) + vmcnt(0) + SBAR(0).
#define LD16S(dst, base, OFF) \
  asm volatile("global_load_dwordx4 %0, %1, off offset:" #OFF " sc0 sc1" \
               : "=v"(dst) : "v"(base) : "memory")
#define LDALLS() do { \
  LD16S(afr[0], bp, 0);   LD16S(afr[1], bp, 64);  \
  LD16S(afr[2], bp, 128); LD16S(afr[3], bp, 192); \
  LD16S(afr[4], bp, 256); LD16S(afr[5], bp, 320); \
  LD16S(afr[6], bp, 384); LD16S(afr[7], bp, 448); } while (0)

// ---------------------------------------------------------------------------
// Persistent scan — R12's kernel (passed, 1459us scan) with one cohesive
// "transaction diet" on the serial IF$ path, all proven primitives:
//  * exchange reads: 32 scalar 4B atomic loads -> 8x dwordx4 sc0sc1 (R7
//    pattern incl. vmcnt(0)+sched_barrier(0); 4x fewer IF$ transactions)
//  * publish: 32x 4B atomic stores/wave -> 16x 8B atomic stores (compiler
//    relaxed agent class, proven; halves the drain queue)
//  * poll backoff s_sleep(2) -> s_sleep(1) (lines are consumer-private)
// Protocol ordering (drain-before-post, mailbox poll) is UNCHANGED.
// ---------------------------------------------------------------------------
__global__ __launch_bounds__(256, 1) void rnn_scan(
    const float* __restrict__ U, const float* __restrict__ X0,
    const float* __restrict__ SN, const float* __restrict__ RN,
    const float* __restrict__ Wi, const float* __restrict__ Bi,
    const float* __restrict__ Wr,
    float* __restrict__ X, float* __restrict__ R,
    unsigned* __restrict__ mail, unsigned* __restrict__ ex)
{
  const int bid   = blockIdx.x;
  const int isl   = bid / BPI, slice = bid % BPI;
  const int tid   = threadIdx.x;
  const int wave  = tid >> 6, lane = tid & 63;
  const int l15   = lane & 15, koct = lane >> 4;
  const int colbase = slice * COLS;

  // --- resident B fragments of W_rec slice: B[k][n] = W_rec[col n][k] ---
  s16x8 bfrag[KT][NT];
#pragma unroll
  for (int kt = 0; kt < KT; ++kt) {
    const int k0 = wave * KW + kt * 32 + koct * 8;
#pragma unroll
    for (int nt = 0; nt < NT; ++nt) {
      const float4* q = (const float4*)(Wr + (size_t)(colbase + nt * 16 + l15) * N_ + k0);
      bfrag[kt][nt] = cvt8(q[0], q[1]);
    }
  }
  // --- W_in fragments: input term split across waves 0,1 (K=64 = 2x32) ---
  s16x8 wifrag[NT];
  if (wave < 2) {
#pragma unroll
    for (int nt = 0; nt < NT; ++nt) {
      const float4* q = (const float4*)(Wi + (size_t)(colbase + nt * 16 + l15) * NIN_ + wave * 32 + koct * 8);
      wifrag[nt] = cvt8(q[0], q[1]);
    }
  }

  // thread (wave, lane) owns state element (batch = wave, col = lane)
  const int cc   = lane;
  const int bloc = wave;
  const int bg   = isl * MB + bloc;                 // global batch
  const int nn   = colbase + cc;                    // global col
  const int abatch = isl * MB + (l15 & 3);          // A-row batch (rows dup 4x)

  float x = X0[nn];
  const float bin = Bi[nn];
  const float r0 = fmaxf(tanhf(x), 0.f);

  __shared__ float part[4][COLS][MB];               // [wave][col][batch^swz]

  // consumer-private poll line; producer post column
  const unsigned* const myline = mail + (isl * BPI + slice) * BPI;  // 64B line
  unsigned* const postcol      = mail + isl * BPI * BPI + slice;    // +c*16

  // publish r_0 into parity-0 exchange buffer (8B compiler wt atomics)
  {
    unsigned short h = f2bf(r0);
    unsigned other = __shfl_xor((unsigned)h, 1);
    unsigned vv  = (unsigned)h | (other << 16);        // cols (nn&~1, nn|1)
    unsigned vv2 = __shfl_xor(vv, 2);                  // cols (+2, +3)
    if ((lane & 3) == 0) {
      uint64_t q8 = (uint64_t)vv | ((uint64_t)vv2 << 32);
      __hip_atomic_store((uint64_t*)(ex + (size_t)bg * (N_ / 2) + (nn >> 1)), q8,
                         __ATOMIC_RELAXED, __HIP_MEMORY_SCOPE_AGENT);
    }
  }
  __syncthreads();   // drains vmcnt for all waves -> ex visible before post
  if (tid < BPI)     // wave0 lanes 0..15: one store per consumer block
    __hip_atomic_store(postcol + tid * BPI, 1u,
                       __ATOMIC_RELAXED, __HIP_MEMORY_SCOPE_AGENT);

  float pxn = 0.f, prv = 0.f;                      // deferred X/R store values

  for (int t = 0; t < T_; ++t) {
    const int par = t & 1;
    const size_t row = (size_t)bg * T_ + t;

    // independent loads issued before the wait (latency hides under spin)
    const float snv = SN[row * N_ + nn];
    const float rnv = RN[row * N_ + nn];
    float4 uq0, uq1;
    if (wave < 2) {
      const float4* q = (const float4*)(U + ((size_t)(isl * MB + (l15 & 3)) * T_ + t) * NIN_
                                          + wave * 32 + koct * 8);
      uq0 = q[0]; uq1 = q[1];
    }

    // per-wave mailbox poll: lane L checks producer slot L&15 on OUR line
    {
      const unsigned need = (unsigned)(t + 1);
      for (;;) {
        unsigned fv = __hip_atomic_load(myline + l15, __ATOMIC_RELAXED,
                                        __HIP_MEMORY_SCOPE_AGENT);
        if (__all((int)(fv >= need))) break;
        __builtin_amdgcn_s_sleep(1);
      }
    }

    // previous step's X/R stores: issued here so their HBM ack overlaps the
    // exchange-load latency (R2/R11/R12 placement; L2-ack, cheap)
    if (t > 0) {
      X[(row - 1) * N_ + nn] = pxn;
      R[(row - 1) * N_ + nn] = prv;
    }

    // A fragments: vectorized coherence-point loads (R7-proven pattern)
    const unsigned* bp = ex + (size_t)par * (B_ * (N_ / 2))
                            + (size_t)abatch * (N_ / 2)
                            + ((wave * KW + koct * 8) >> 1);
    s16x8 afr[KT];
    LDALLS();
    asm volatile("s_waitcnt vmcnt(0)" ::: "memory");
    __builtin_amdgcn_sched_barrier(0);   // rule #18: keep MFMA below the wait

    f32x4 acc[NT];
#pragma unroll
    for (int nt = 0; nt < NT; ++nt) acc[nt] = f32x4{0.f, 0.f, 0.f, 0.f};
#pragma unroll
    for (int kt = 0; kt < KT; ++kt)
#pragma unroll
      for (int nt = 0; nt < NT; ++nt)
        acc[nt] = __builtin_amdgcn_mfma_f32_16x16x32_bf16(afr[kt], bfrag[kt][nt], acc[nt], 0, 0, 0);
    if (wave < 2) {
      s16x8 ua = cvt8(uq0, uq1);
#pragma unroll
      for (int nt = 0; nt < NT; ++nt)
        acc[nt] = __builtin_amdgcn_mfma_f32_16x16x32_bf16(ua, wifrag[nt], acc[nt], 0, 0, 0);
    }

    // cross-wave K-partials; XOR-swizzled slot layout (R4-proven, conflict-0)
    if (lane < 16) {
#pragma unroll
      for (int nt = 0; nt < NT; ++nt) {
        const int s = (nt * 2 + (lane >> 3)) & 3;
        f32x4 a = acc[nt];
        if (s & 1) a = f32x4{a[1], a[0], a[3], a[2]};
        if (s & 2) a = f32x4{a[2], a[3], a[0], a[1]};
        *(f32x4*)&part[wave][nt * 16 + lane][0] = a;   // slot j holds acc[j^s]
      }
    }
    __syncthreads();
    const int sr = (cc >> 3) & 3;
    const float mat = part[0][cc][bloc ^ sr] + part[1][cc][bloc ^ sr] +
                      part[2][cc][bloc ^ sr] + part[3][cc][bloc ^ sr];
    const float xn = x + 0.1f * (-x + mat + bin + snv);
    const float rv = fmaxf(tanhf(xn), 0.f) + rnv;
    x = xn;

    // publish r_{t+1} (8B compiler wt atomics; halves drain queue depth)
    {
      unsigned short h = f2bf(rv);
      unsigned other = __shfl_xor((unsigned)h, 1);
      unsigned vv  = (unsigned)h | (other << 16);
      unsigned vv2 = __shfl_xor(vv, 2);
      if ((lane & 3) == 0) {
        uint64_t q8 = (uint64_t)vv | ((uint64_t)vv2 << 32);
        __hip_atomic_store((uint64_t*)(ex + (size_t)(par ^ 1) * (B_ * (N_ / 2)) +
                                       (size_t)bg * (N_ / 2) + (nn >> 1)), q8,
                           __ATOMIC_RELAXED, __HIP_MEMORY_SCOPE_AGENT);
      }
    }
    __syncthreads();   // B_drain: all waves' ex stores drained, then post
    if (tid < BPI)     // 16 mailbox stores to 16 consumer-private lines
      __hip_atomic_store(postcol + tid * BPI, (unsigned)(t + 2),
                         __ATOMIC_RELAXED, __HIP_MEMORY_SCOPE_AGENT);

    pxn = xn; prv = rv;
  }
  // final deferred store
  {
    const size_t lrow = (size_t)bg * T_ + (T_ - 1);
    X[lrow * N_ + nn] = pxn;
    R[lrow * N_ + nn] = prv;
  }
}

// ---------------------------------------------------------------------------
// Z = R @ W_out^T + b_out + output_noise.  W_out register-resident; R rows
// double-buffered in LDS; one barrier per row; 512 blocks (R6/R7/R11-proven).
// ---------------------------------------------------------------------------
#define TCH 64
__global__ __launch_bounds__(256, 2) void rnn_zout(
    const float* __restrict__ Rm, const float* __restrict__ ON,
    const float* __restrict__ Wo, const float* __restrict__ Bo,
    float* __restrict__ Z)
{
  const int bid = blockIdx.x;
  const int b = bid >> 3, tq = bid & 7;
  const int tid = threadIdx.x;
  const int o = tid & 31, kc = tid >> 5;

  float4 wv[32];
  const float4* wp = (const float4*)(Wo + (size_t)o * N_ + kc * 128);
#pragma unroll
  for (int i = 0; i < 32; ++i) wv[i] = wp[i];
  const float bo = Bo[o];

  __shared__ float Rl[2][N_];
  __shared__ float zred[2][8][32];

  const int t0 = tq * TCH;
  ((float4*)Rl[0])[tid] = ((const float4*)(Rm + ((size_t)b * T_ + t0) * N_))[tid];
  __syncthreads();

  for (int i = 0; i < TCH; ++i) {
    const int cur = i & 1;
    const size_t row = (size_t)b * T_ + t0 + i;
    float4 nx;
    if (i + 1 < TCH)
      nx = ((const float4*)(Rm + (row + 1) * N_))[tid];
    float a0 = 0.f;
#pragma unroll
    for (int j = 0; j < 32; ++j) {
      const float* rp = &Rl[cur][kc * 128 + j * 4];
      a0 += wv[j].x * rp[0] + wv[j].y * rp[1] + wv[j].z * rp[2] + wv[j].w * rp[3];
    }
    if (i + 1 < TCH)
      ((float4*)Rl[cur ^ 1])[tid] = nx;
    zred[cur][kc][o] = a0;
    __syncthreads();
    if (tid < 32) {
      float z = bo;
#pragma unroll
      for (int k = 0; k < 8; ++k) z += zred[cur][k][tid];
      Z[row * NOUT_ + tid] = z + ON[row * NOUT_ + tid];
    }
    // reduce(i) reads zred[cur] after barrier(i); the next write to the same
    // zred/Rl buffer happens only after barrier(i+1) gates it. Race-free.
  }
}

extern "C" void kernel_launch(void* const* d_in, const int* in_sizes, int n_in,
                              void* d_out, int out_size, void* d_ws, size_t ws_size,
                              hipStream_t stream) {
  const float* U  = (const float*)d_in[0];
  const float* X0 = (const float*)d_in[1];
  const float* SN = (const float*)d_in[2];
  const float* RN = (const float*)d_in[3];
  const float* ON = (const float*)d_in[4];
  const float* Wi = (const float*)d_in[5];
  const float* Bi = (const float*)d_in[6];
  const float* Wr = (const float*)d_in[7];
  const float* Wo = (const float*)d_in[8];
  const float* Bo = (const float*)d_in[9];

  float* X = (float*)d_out;
  float* R = X + (size_t)B_ * T_ * N_;
  float* Z = R + (size_t)B_ * T_ * N_;

  unsigned* mail = (unsigned*)d_ws;                        // [NISL][16][16]
  unsigned* ex   = (unsigned*)((char*)d_ws + 65536);       // [2][B_][N_/2] bf16x2

  // zero mailboxes every call (graph-capture-safe; 0 < first need of 1)
  hipMemsetAsync(mail, 0, MAIL_WORDS * sizeof(unsigned), stream);

  hipLaunchKernelGGL(rnn_scan, dim3(NISL * BPI), dim3(256), 0, stream,
                     U, X0, SN, RN, Wi, Bi, Wr, X, R, mail, ex);
  hipLaunchKernelGGL(rnn_zout, dim3(B_ * (T_ / TCH)), dim3(256), 0, stream,
                     R, ON, Wo, Bo, Z);
}